// Round 1
// baseline (435.180 us; speedup 1.0000x reference)
//
#include <hip/hip_runtime.h>

// out = clip(x + noise, 0, 1) — pure memory-bound elementwise op.
// 50,331,648 fp32 elements: 604 MB traffic -> ~96 us floor at 6.3 TB/s.

__global__ __launch_bounds__(256) void gaussian_noise_clip_kernel(
    const float4* __restrict__ x,
    const float4* __restrict__ noise,
    float4* __restrict__ out,
    int n4) {
    int idx = blockIdx.x * blockDim.x + threadIdx.x;
    int stride = gridDim.x * blockDim.x;
    for (int i = idx; i < n4; i += stride) {
        float4 a = x[i];
        float4 b = noise[i];
        float4 r;
        r.x = fminf(fmaxf(a.x + b.x, 0.0f), 1.0f);
        r.y = fminf(fmaxf(a.y + b.y, 0.0f), 1.0f);
        r.z = fminf(fmaxf(a.z + b.z, 0.0f), 1.0f);
        r.w = fminf(fmaxf(a.w + b.w, 0.0f), 1.0f);
        out[i] = r;
    }
}

// Scalar tail (not exercised at this size since n % 4 == 0, kept for safety).
__global__ __launch_bounds__(256) void gaussian_noise_clip_tail(
    const float* __restrict__ x,
    const float* __restrict__ noise,
    float* __restrict__ out,
    int start, int n) {
    int i = start + blockIdx.x * blockDim.x + threadIdx.x;
    if (i < n) {
        out[i] = fminf(fmaxf(x[i] + noise[i], 0.0f), 1.0f);
    }
}

extern "C" void kernel_launch(void* const* d_in, const int* in_sizes, int n_in,
                              void* d_out, int out_size, void* d_ws, size_t ws_size,
                              hipStream_t stream) {
    const float* x     = (const float*)d_in[0];
    const float* noise = (const float*)d_in[1];
    float* out         = (float*)d_out;

    int n  = in_sizes[0];      // 50,331,648
    int n4 = n / 4;            // 12,582,912 float4s

    const int block = 256;
    // Full grid (49152 blocks) — simple one-pass coverage, still coalesced.
    int grid = (n4 + block - 1) / block;
    if (grid > 0) {
        gaussian_noise_clip_kernel<<<grid, block, 0, stream>>>(
            (const float4*)x, (const float4*)noise, (float4*)out, n4);
    }

    int tail_start = n4 * 4;
    int tail = n - tail_start;
    if (tail > 0) {
        int tgrid = (tail + block - 1) / block;
        gaussian_noise_clip_tail<<<tgrid, block, 0, stream>>>(
            x, noise, out, tail_start, n);
    }
}